// Round 3
// baseline (292.267 us; speedup 1.0000x reference)
//
#include <hip/hip_runtime.h>
#include <math.h>

#define BH    32      // B*H
#define NSEQ  8192
#define DDIM  64
#define NPROJ 7
#define BLK   256
#define NB    32      // NSEQ / BLK
#define PITCH 72      // f16 pitch for K/V/O rows (144 B, 16B-aligned)
#define PPITCH 40     // f16 pitch for P rows (32 keys + 8 pad)
#define LOG2E 1.44269504f
#define SC2   0.180336881f   // 0.125 * log2(e)

typedef _Float16 v8h __attribute__((ext_vector_type(8)));
typedef _Float16 v4h __attribute__((ext_vector_type(4)));
typedef float    v4f __attribute__((ext_vector_type(4)));

// ---------------------------------------------------------------------------
// Kernel 1: LSH hash, one row per thread. fp64 sign decisions (borderline
// signs are the only sort-mismatch hazard). Gray code = code ^ (code>>1).
// ---------------------------------------------------------------------------
__global__ __launch_bounds__(256) void hash_kernel(
        const float* __restrict__ query,
        const float* __restrict__ key,
        const float* __restrict__ proj,     // [64][7]
        int* __restrict__ buckets)          // [2][BH*NSEQ]
{
    const float* x = (blockIdx.y == 0) ? query : key;
    const int t = threadIdx.x;
    const int row = blockIdx.x * 256 + t;

    __shared__ double pdd[64 * NPROJ];
    for (int i = t; i < 64 * NPROJ; i += 256) pdd[i] = (double)proj[i];
    __syncthreads();

    const float4* rp = (const float4*)(x + (size_t)row * DDIM);
    double acc[NPROJ];
    #pragma unroll
    for (int r = 0; r < NPROJ; ++r) acc[r] = 0.0;

    #pragma unroll
    for (int i = 0; i < 16; ++i) {
        float4 v = rp[i];
        float e[4] = {v.x, v.y, v.z, v.w};
        #pragma unroll
        for (int c = 0; c < 4; ++c) {
            double xv = (double)e[c];
            const int d = i * 4 + c;
            #pragma unroll
            for (int r = 0; r < NPROJ; ++r)
                acc[r] += xv * pdd[d * NPROJ + r];
        }
    }
    int code = 0;
    #pragma unroll
    for (int r = 0; r < NPROJ; ++r)
        if (acc[r] > 0.0) code |= (1 << r);
    buckets[(size_t)blockIdx.y * (BH * NSEQ) + row] = code ^ (code >> 1);
}

// ---------------------------------------------------------------------------
// Kernel 2: stable counting sort, one 256-thread block per (tensor, bh).
// ---------------------------------------------------------------------------
#define SCNT 258
__global__ __launch_bounds__(256) void sort_kernel(
        const int* __restrict__ buckets,
        int* __restrict__ q_idx,
        int* __restrict__ k_idx)
{
    const int bh = blockIdx.x;
    const int t = threadIdx.x;
    const int lane = t & 63, w = t >> 6;
    const int* b = buckets + (size_t)blockIdx.y * (BH * NSEQ) + (size_t)bh * NSEQ;
    int* out = ((blockIdx.y == 0) ? q_idx : k_idx) + (size_t)bh * NSEQ;

    __shared__ unsigned short cnt[128 * SCNT];
    __shared__ unsigned int partial[256];
    __shared__ unsigned int wsum[4];

    unsigned int* cz = (unsigned int*)cnt;
    for (int i = t; i < 128 * SCNT / 2; i += 256) cz[i] = 0;

    int4 rv[8];
    const int4* b4 = (const int4*)b;
    #pragma unroll
    for (int s = 0; s < 8; ++s) rv[s] = b4[t * 8 + s];
    __syncthreads();

    #pragma unroll
    for (int s = 0; s < 8; ++s) {
        cnt[rv[s].x * SCNT + t]++;
        cnt[rv[s].y * SCNT + t]++;
        cnt[rv[s].z * SCNT + t]++;
        cnt[rv[s].w * SCNT + t]++;
    }
    __syncthreads();

    const int v0 = t >> 1, tt0 = (t & 1) * 128;
    {
        unsigned int s = 0;
        for (int j = 0; j < 128; ++j) s += cnt[v0 * SCNT + tt0 + j];
        partial[t] = s;
    }
    __syncthreads();

    unsigned int chunkoff;
    {
        unsigned int x = partial[t], own = x;
        #pragma unroll
        for (int d = 1; d < 64; d <<= 1) {
            unsigned int y = __shfl_up(x, d);
            if (lane >= d) x += y;
        }
        if (lane == 63) wsum[w] = x;
        __syncthreads();
        unsigned int wb0 = 0;
        if (w == 1) wb0 = wsum[0];
        else if (w == 2) wb0 = wsum[0] + wsum[1];
        else if (w == 3) wb0 = wsum[0] + wsum[1] + wsum[2];
        chunkoff = x - own + wb0;
    }

    {
        unsigned int s = chunkoff;
        for (int j = 0; j < 128; ++j) {
            unsigned short c = cnt[v0 * SCNT + tt0 + j];
            cnt[v0 * SCNT + tt0 + j] = (unsigned short)s;
            s += c;
        }
    }
    __syncthreads();

    const int i0 = t * 32;
    #pragma unroll
    for (int s = 0; s < 8; ++s) {
        int4 q = rv[s];
        int j4 = i0 + s * 4;
        { unsigned short p = cnt[q.x * SCNT + t]++; out[p] = j4 + 0; }
        { unsigned short p = cnt[q.y * SCNT + t]++; out[p] = j4 + 1; }
        { unsigned short p = cnt[q.z * SCNT + t]++; out[p] = j4 + 2; }
        { unsigned short p = cnt[q.w * SCNT + t]++; out[p] = j4 + 3; }
    }
}

// ---------------------------------------------------------------------------
// Kernel 3: MFMA attention, transposed dataflow.
//   S^T = K . Q^T   (C-layout: row=key, col=query -> P stored [q][k], b64)
//   O^T = V^T . P^T (A=V^T from Vt[d][key], B=P^T from P[q][k], both b128)
//   l   = per-lane scalar sum of f16 P values, quad-reduced via shfl_xor
//
// R3 reshape: 512 threads / 8 waves per block, 32 queries per wave (same
// 256-query tile -> gather traffic unchanged). Per-thread registers halve
// (Oacc 32, qf 16, prefetch 16) -> fits 128-reg budget -> 4 waves/SIMD =
// 16 waves/CU, 2x the TLP of the 256-thread shape (which needed ~176 regs
// and capped at 2 waves/SIMD). T14 prefetch kept: next chunk's K/V rows
// load into registers while current chunk computes.
// ---------------------------------------------------------------------------
__global__ __launch_bounds__(512, 4) void attn_kernel(
        const float* __restrict__ query,
        const float* __restrict__ key,
        const float* __restrict__ value,
        const int* __restrict__ sampled,
        const int* __restrict__ q_idx,
        const int* __restrict__ k_idx,
        float* __restrict__ outp)
{
    const int qb = blockIdx.x;
    const int bh = blockIdx.y;
    const int t  = threadIdx.x;
    const int w    = t >> 6;       // wave -> queries [w*32, w*32+32)
    const int lane = t & 63;
    const int quad = lane >> 4;
    const int nrow = lane & 15;

    __shared__ __align__(16) unsigned char smem[38912];
    _Float16* Kc = (_Float16*)smem;                 // 64*72*2    = 9216 B
    _Float16* Vt = (_Float16*)(smem + 9216);        // 64*72*2    = 9216 B
    _Float16* Pb = (_Float16*)(smem + 18432);       // 8*32*40*2  = 20480 B
    _Float16* Ob = (_Float16*)smem;                 // epilogue: 256*72*2 = 36864 B
    __shared__ int s_row[512];
    __shared__ __align__(16) float lb[512];
    __shared__ int s_qi[256];
    __shared__ int wb[4];

    const size_t bhN = (size_t)bh * NSEQ;

    // ---- setup (first 4 waves own the 256 elements) ----
    int ss = 0, sb = 0;
    if (t < 256) {
        s_qi[t] = q_idx[bhN + qb * BLK + t];
        s_row[t] = k_idx[bhN + qb * BLK + t];
        ss = sampled[bh * BLK + t];
        s_row[256 + t] = k_idx[bhN + ss];
        sb = ss >> 8;
        unsigned long long mk = __ballot(sb == qb);
        if (lane == 0) wb[w] = __popcll(mk);
    }
    __syncthreads();
    if (t < 256) {
        int cnt_in = wb[0] + wb[1] + wb[2] + wb[3];
        float J = __logf((float)(NSEQ - BLK) / (float)(BLK - cnt_in));
        lb[t] = -6.0f * LOG2E;
        lb[256 + t] = (sb == qb) ? -3.0e4f : (J - 6.0f) * LOG2E;
    }

    // ---- staging geometry (constant per thread) ----
    const int kr_r = t >> 3, kr_seg = t & 7;   // K: 1 row, 32 B (2 float4)
    const int vs_kq = t & 15, vs_dg = t >> 4;  // V: 4 rows, 8 B (float2) each

    float4 kreg0, kreg1;
    float2 vreg0, vreg1, vreg2, vreg3;

    #define ISSUE_LOADS(ch_) do {                                              \
        int krow_ = s_row[(ch_) * 64 + kr_r];                                  \
        const float4* kp_ = (const float4*)(key + (bhN + (size_t)krow_) * DDIM \
                                            + kr_seg * 8);                     \
        kreg0 = kp_[0]; kreg1 = kp_[1];                                        \
        int vr0_ = s_row[(ch_) * 64 + vs_kq * 4 + 0];                          \
        int vr1_ = s_row[(ch_) * 64 + vs_kq * 4 + 1];                          \
        int vr2_ = s_row[(ch_) * 64 + vs_kq * 4 + 2];                          \
        int vr3_ = s_row[(ch_) * 64 + vs_kq * 4 + 3];                          \
        vreg0 = *(const float2*)(value + (bhN + (size_t)vr0_) * DDIM + vs_dg * 2); \
        vreg1 = *(const float2*)(value + (bhN + (size_t)vr1_) * DDIM + vs_dg * 2); \
        vreg2 = *(const float2*)(value + (bhN + (size_t)vr2_) * DDIM + vs_dg * 2); \
        vreg3 = *(const float2*)(value + (bhN + (size_t)vr3_) * DDIM + vs_dg * 2); \
    } while (0)

    // chunk-0 loads in flight while we gather Q fragments
    ISSUE_LOADS(0);

    // ---- Q fragments (per-lane: Q[w*32+ni*16+nrow][k2*32+quad*8+j]) ----
    v8h qf[2][2];
    #pragma unroll
    for (int ni = 0; ni < 2; ++ni) {
        int qi = s_qi[w * 32 + ni * 16 + nrow];
        const float* qp = query + (bhN + (size_t)qi) * DDIM;
        #pragma unroll
        for (int k2 = 0; k2 < 2; ++k2) {
            const float4* q4 = (const float4*)(qp + k2 * 32 + quad * 8);
            float4 a = q4[0], bvec = q4[1];
            v8h h;
            h[0]=(_Float16)a.x; h[1]=(_Float16)a.y; h[2]=(_Float16)a.z; h[3]=(_Float16)a.w;
            h[4]=(_Float16)bvec.x; h[5]=(_Float16)bvec.y; h[6]=(_Float16)bvec.z; h[7]=(_Float16)bvec.w;
            qf[ni][k2] = h;
        }
    }

    v4f Oacc[4][2];   // [d-tile][q-tile]: O^T rows d=mi2*16+quad*4+r, col q=ni*16+nrow
    float l_part[2];  // per-lane partial of l[q=ni*16+nrow] (this quad's keys)
    #pragma unroll
    for (int ni = 0; ni < 2; ++ni) {
        l_part[ni] = 0.f;
        #pragma unroll
        for (int mi2 = 0; mi2 < 4; ++mi2) Oacc[mi2][ni] = (v4f){0.f, 0.f, 0.f, 0.f};
    }
    _Float16* Pw = Pb + w * 32 * PPITCH;

    #pragma unroll 1
    for (int ch = 0; ch < 8; ++ch) {
        __syncthreads();
        // ---- write staged K (regs -> f16 LDS, row-major [key][d]) ----
        {
            v8h h0;
            h0[0]=(_Float16)kreg0.x; h0[1]=(_Float16)kreg0.y; h0[2]=(_Float16)kreg0.z; h0[3]=(_Float16)kreg0.w;
            h0[4]=(_Float16)kreg1.x; h0[5]=(_Float16)kreg1.y; h0[6]=(_Float16)kreg1.z; h0[7]=(_Float16)kreg1.w;
            *(v8h*)&Kc[kr_r * PITCH + kr_seg * 8] = h0;
        }
        // ---- write staged V transposed [d][key] with packed b64 writes ----
        {
            v4h h0, h1;
            h0[0]=(_Float16)vreg0.x; h0[1]=(_Float16)vreg1.x; h0[2]=(_Float16)vreg2.x; h0[3]=(_Float16)vreg3.x;
            h1[0]=(_Float16)vreg0.y; h1[1]=(_Float16)vreg1.y; h1[2]=(_Float16)vreg2.y; h1[3]=(_Float16)vreg3.y;
            *(v4h*)&Vt[(vs_dg * 2 + 0) * PITCH + vs_kq * 4] = h0;
            *(v4h*)&Vt[(vs_dg * 2 + 1) * PITCH + vs_kq * 4] = h1;
        }
        // prefetch next chunk's K/V into the now-free registers;
        // latency hides under this chunk's MFMA+exp compute
        if (ch < 7) ISSUE_LOADS(ch + 1);
        __syncthreads();

        #pragma unroll
        for (int ks = 0; ks < 2; ++ks) {
            // ---- S^T = K.Q^T over 32 keys, exp, store P[q][k] (b64) ----
            #pragma unroll
            for (int mi = 0; mi < 2; ++mi) {
                v4f bb = *(const v4f*)&lb[ch * 64 + ks * 32 + mi * 16 + quad * 4];
                const int krow = ks * 32 + mi * 16 + nrow;
                v8h ka0 = *(const v8h*)&Kc[krow * PITCH + quad * 8];
                v8h ka1 = *(const v8h*)&Kc[krow * PITCH + 32 + quad * 8];
                #pragma unroll
                for (int ni = 0; ni < 2; ++ni) {
                    v4f S = (v4f){0.f, 0.f, 0.f, 0.f};
                    S = __builtin_amdgcn_mfma_f32_16x16x32_f16(ka0, qf[ni][0], S, 0, 0, 0);
                    S = __builtin_amdgcn_mfma_f32_16x16x32_f16(ka1, qf[ni][1], S, 0, 0, 0);
                    v4h ph;
                    #pragma unroll
                    for (int r = 0; r < 4; ++r)
                        ph[r] = (_Float16)__builtin_amdgcn_exp2f(fmaf(S[r], SC2, bb[r]));
                    l_part[ni] += ((float)ph[0] + (float)ph[1])
                                + ((float)ph[2] + (float)ph[3]);
                    *(v4h*)&Pw[(ni * 16 + nrow) * PPITCH + mi * 16 + quad * 4] = ph;
                }
            }
            // ---- load P^T frags, accumulate O^T ----
            v8h pbv[2];
            #pragma unroll
            for (int ni = 0; ni < 2; ++ni)
                pbv[ni] = *(const v8h*)&Pw[(ni * 16 + nrow) * PPITCH + quad * 8];
            __builtin_amdgcn_s_setprio(1);
            #pragma unroll
            for (int mi2 = 0; mi2 < 4; ++mi2) {
                v8h va = *(const v8h*)&Vt[(mi2 * 16 + nrow) * PITCH + ks * 32 + quad * 8];
                #pragma unroll
                for (int ni = 0; ni < 2; ++ni)
                    Oacc[mi2][ni] = __builtin_amdgcn_mfma_f32_16x16x32_f16(va, pbv[ni], Oacc[mi2][ni], 0, 0, 0);
            }
            __builtin_amdgcn_s_setprio(0);
        }
    }

    // ---- normalize, write O (f16) to [q][d] pool, cooperative scatter ----
    __syncthreads();
    #pragma unroll
    for (int ni = 0; ni < 2; ++ni) {
        float l = l_part[ni];
        l += __shfl_xor(l, 16);
        l += __shfl_xor(l, 32);
        float inv = 1.0f / l;
        #pragma unroll
        for (int mi2 = 0; mi2 < 4; ++mi2) {
            v4h h;
            #pragma unroll
            for (int r = 0; r < 4; ++r)
                h[r] = (_Float16)(Oacc[mi2][ni][r] * inv);
            *(v4h*)&Ob[(w * 32 + ni * 16 + nrow) * PITCH + mi2 * 16 + quad * 4] = h;
        }
    }
    __syncthreads();

    #pragma unroll
    for (int p = 0; p < 2; ++p) {
        int row = p * 128 + (t >> 2);
        int seg = t & 3;
        const _Float16* src = &Ob[row * PITCH + seg * 16];
        v8h x0 = *(const v8h*)src;
        v8h x1 = *(const v8h*)(src + 8);
        int qi = s_qi[row];
        float4* op = (float4*)(outp + (bhN + (size_t)qi) * DDIM + seg * 16);
        op[0] = make_float4((float)x0[0], (float)x0[1], (float)x0[2], (float)x0[3]);
        op[1] = make_float4((float)x0[4], (float)x0[5], (float)x0[6], (float)x0[7]);
        op[2] = make_float4((float)x1[0], (float)x1[1], (float)x1[2], (float)x1[3]);
        op[3] = make_float4((float)x1[4], (float)x1[5], (float)x1[6], (float)x1[7]);
    }
}

// ---------------------------------------------------------------------------
extern "C" void kernel_launch(void* const* d_in, const int* in_sizes, int n_in,
                              void* d_out, int out_size, void* d_ws, size_t ws_size,
                              hipStream_t stream) {
    (void)in_sizes; (void)n_in; (void)out_size; (void)ws_size;
    const float* query = (const float*)d_in[0];
    const float* key   = (const float*)d_in[1];
    const float* value = (const float*)d_in[2];
    const float* proj  = (const float*)d_in[3];
    const int* sampled = (const int*)d_in[4];
    float* out = (float*)d_out;

    int* buckets = (int*)d_ws;
    int* q_idx   = buckets + 2 * BH * NSEQ;
    int* k_idx   = q_idx + BH * NSEQ;

    hash_kernel<<<dim3(BH * NSEQ / 256, 2), 256, 0, stream>>>(query, key, proj, buckets);
    sort_kernel<<<dim3(BH, 2), 256, 0, stream>>>(buckets, q_idx, k_idx);
    attn_kernel<<<dim3(NB, BH), 512, 0, stream>>>(query, key, value, sampled,
                                                  q_idx, k_idx, out);
}

// Round 4
// 286.932 us; speedup vs baseline: 1.0186x; 1.0186x over previous
//
#include <hip/hip_runtime.h>
#include <math.h>

#define BH    32      // B*H
#define NSEQ  8192
#define DDIM  64
#define NPROJ 7
#define BLK   256
#define NB    32      // NSEQ / BLK
#define PITCH 72      // f16 pitch for K/V/O rows (144 B, 16B-aligned)
#define PPITCH 40     // f16 pitch for P rows (32 keys + 8 pad)
#define LOG2E 1.44269504f
#define SC2   0.180336881f   // 0.125 * log2(e)

typedef _Float16 v8h __attribute__((ext_vector_type(8)));
typedef _Float16 v4h __attribute__((ext_vector_type(4)));
typedef float    v4f __attribute__((ext_vector_type(4)));

// ---------------------------------------------------------------------------
// Kernel 1: LSH hash, one row per thread. fp64 sign decisions (borderline
// signs are the only sort-mismatch hazard). Gray code = code ^ (code>>1).
// ---------------------------------------------------------------------------
__global__ __launch_bounds__(256) void hash_kernel(
        const float* __restrict__ query,
        const float* __restrict__ key,
        const float* __restrict__ proj,     // [64][7]
        int* __restrict__ buckets)          // [2][BH*NSEQ]
{
    const float* x = (blockIdx.y == 0) ? query : key;
    const int t = threadIdx.x;
    const int row = blockIdx.x * 256 + t;

    __shared__ double pdd[64 * NPROJ];
    for (int i = t; i < 64 * NPROJ; i += 256) pdd[i] = (double)proj[i];
    __syncthreads();

    const float4* rp = (const float4*)(x + (size_t)row * DDIM);
    double acc[NPROJ];
    #pragma unroll
    for (int r = 0; r < NPROJ; ++r) acc[r] = 0.0;

    #pragma unroll
    for (int i = 0; i < 16; ++i) {
        float4 v = rp[i];
        float e[4] = {v.x, v.y, v.z, v.w};
        #pragma unroll
        for (int c = 0; c < 4; ++c) {
            double xv = (double)e[c];
            const int d = i * 4 + c;
            #pragma unroll
            for (int r = 0; r < NPROJ; ++r)
                acc[r] += xv * pdd[d * NPROJ + r];
        }
    }
    int code = 0;
    #pragma unroll
    for (int r = 0; r < NPROJ; ++r)
        if (acc[r] > 0.0) code |= (1 << r);
    buckets[(size_t)blockIdx.y * (BH * NSEQ) + row] = code ^ (code >> 1);
}

// ---------------------------------------------------------------------------
// Kernel 2: stable counting sort, one 256-thread block per (tensor, bh).
// ---------------------------------------------------------------------------
#define SCNT 258
__global__ __launch_bounds__(256) void sort_kernel(
        const int* __restrict__ buckets,
        int* __restrict__ q_idx,
        int* __restrict__ k_idx)
{
    const int bh = blockIdx.x;
    const int t = threadIdx.x;
    const int lane = t & 63, w = t >> 6;
    const int* b = buckets + (size_t)blockIdx.y * (BH * NSEQ) + (size_t)bh * NSEQ;
    int* out = ((blockIdx.y == 0) ? q_idx : k_idx) + (size_t)bh * NSEQ;

    __shared__ unsigned short cnt[128 * SCNT];
    __shared__ unsigned int partial[256];
    __shared__ unsigned int wsum[4];

    unsigned int* cz = (unsigned int*)cnt;
    for (int i = t; i < 128 * SCNT / 2; i += 256) cz[i] = 0;

    int4 rv[8];
    const int4* b4 = (const int4*)b;
    #pragma unroll
    for (int s = 0; s < 8; ++s) rv[s] = b4[t * 8 + s];
    __syncthreads();

    #pragma unroll
    for (int s = 0; s < 8; ++s) {
        cnt[rv[s].x * SCNT + t]++;
        cnt[rv[s].y * SCNT + t]++;
        cnt[rv[s].z * SCNT + t]++;
        cnt[rv[s].w * SCNT + t]++;
    }
    __syncthreads();

    const int v0 = t >> 1, tt0 = (t & 1) * 128;
    {
        unsigned int s = 0;
        for (int j = 0; j < 128; ++j) s += cnt[v0 * SCNT + tt0 + j];
        partial[t] = s;
    }
    __syncthreads();

    unsigned int chunkoff;
    {
        unsigned int x = partial[t], own = x;
        #pragma unroll
        for (int d = 1; d < 64; d <<= 1) {
            unsigned int y = __shfl_up(x, d);
            if (lane >= d) x += y;
        }
        if (lane == 63) wsum[w] = x;
        __syncthreads();
        unsigned int wb0 = 0;
        if (w == 1) wb0 = wsum[0];
        else if (w == 2) wb0 = wsum[0] + wsum[1];
        else if (w == 3) wb0 = wsum[0] + wsum[1] + wsum[2];
        chunkoff = x - own + wb0;
    }

    {
        unsigned int s = chunkoff;
        for (int j = 0; j < 128; ++j) {
            unsigned short c = cnt[v0 * SCNT + tt0 + j];
            cnt[v0 * SCNT + tt0 + j] = (unsigned short)s;
            s += c;
        }
    }
    __syncthreads();

    const int i0 = t * 32;
    #pragma unroll
    for (int s = 0; s < 8; ++s) {
        int4 q = rv[s];
        int j4 = i0 + s * 4;
        { unsigned short p = cnt[q.x * SCNT + t]++; out[p] = j4 + 0; }
        { unsigned short p = cnt[q.y * SCNT + t]++; out[p] = j4 + 1; }
        { unsigned short p = cnt[q.z * SCNT + t]++; out[p] = j4 + 2; }
        { unsigned short p = cnt[q.w * SCNT + t]++; out[p] = j4 + 3; }
    }
}

// ---------------------------------------------------------------------------
// Kernel 3: MFMA attention, transposed dataflow (4 waves x 64 queries).
//   S^T = K . Q^T   (C-layout: row=key, col=query -> P stored [q][k], b64)
//   O^T = V^T . P^T (A=V^T from Vt[d][key], B=P^T from P[q][k], both b128)
//   l   = per-lane scalar sum of f16 P values, quad-reduced via shfl_xor
//
// R4: LDS-double-buffered K/V with ONE raw barrier per chunk.
// __syncthreads() lowers to "s_waitcnt vmcnt(0) lgkmcnt(0); s_barrier",
// which DRAINED the prefetched gathers at the barrier every chunk (the
// real reason R0-R3 sat at ~92-101us with every pipe <40%). The raw
// barrier waits only lgkmcnt(0) (LDS-write visibility), leaving the
// ch+1 gathers in flight across the barrier; they are vmcnt-waited only
// at their consumption (next chunk's stage-write), fully covered by
// compute(ch). Race-free: writes for ch+1 target buf[(ch+1)&1] while
// compute(ch) reads buf[ch&1]; all waves passed barrier(ch) => all
// finished compute(ch-1) on buf[(ch+1)&1].
// ---------------------------------------------------------------------------
__global__ __launch_bounds__(256, 2) void attn_kernel(
        const float* __restrict__ query,
        const float* __restrict__ key,
        const float* __restrict__ value,
        const int* __restrict__ sampled,
        const int* __restrict__ q_idx,
        const int* __restrict__ k_idx,
        float* __restrict__ outp)
{
    const int qb = blockIdx.x;
    const int bh = blockIdx.y;
    const int t  = threadIdx.x;
    const int w    = t >> 6;       // wave -> queries [w*64, w*64+64)
    const int lane = t & 63;
    const int quad = lane >> 4;
    const int nrow = lane & 15;

    // dbuf: [buf p] Kc at p*18432, Vt at p*18432+9216 ; Pb on top.
    __shared__ __align__(16) unsigned char smem[57344];
    _Float16* Pb = (_Float16*)(smem + 36864);       // 4*64*40*2 = 20480 B
    _Float16* Ob = (_Float16*)smem;                 // epilogue alias: 256*72*2 = 36864 B
    __shared__ int s_row[512];
    __shared__ __align__(16) float lb[512];
    __shared__ int s_qi[256];
    __shared__ int wb[4];

    const size_t bhN = (size_t)bh * NSEQ;

    // ---- setup ----
    {
        s_qi[t] = q_idx[bhN + qb * BLK + t];
        s_row[t] = k_idx[bhN + qb * BLK + t];
        int ss = sampled[bh * BLK + t];
        s_row[256 + t] = k_idx[bhN + ss];
        int sb = ss >> 8;
        unsigned long long mk = __ballot(sb == qb);
        if (lane == 0) wb[w] = __popcll(mk);
        __syncthreads();
        int cnt_in = wb[0] + wb[1] + wb[2] + wb[3];
        float J = __logf((float)(NSEQ - BLK) / (float)(BLK - cnt_in));
        lb[t] = -6.0f * LOG2E;
        lb[256 + t] = (sb == qb) ? -3.0e4f : (J - 6.0f) * LOG2E;
    }

    // ---- staging geometry (constant per thread) ----
    const int kr_r = t >> 2, kr_seg = t & 3;   // K: 1 row, 64B contiguous
    const int vs_kq = t & 15, vs_dg = t >> 4;  // V: 4 rows, 16B each

    float4 kreg0, kreg1, kreg2, kreg3;
    float4 vreg0, vreg1, vreg2, vreg3;

    #define ISSUE_LOADS(ch_) do {                                              \
        int krow_ = s_row[(ch_) * 64 + kr_r];                                  \
        const float4* kp_ = (const float4*)(key + (bhN + (size_t)krow_) * DDIM \
                                            + kr_seg * 16);                    \
        kreg0 = kp_[0]; kreg1 = kp_[1]; kreg2 = kp_[2]; kreg3 = kp_[3];        \
        int vr0_ = s_row[(ch_) * 64 + vs_kq * 4 + 0];                          \
        int vr1_ = s_row[(ch_) * 64 + vs_kq * 4 + 1];                          \
        int vr2_ = s_row[(ch_) * 64 + vs_kq * 4 + 2];                          \
        int vr3_ = s_row[(ch_) * 64 + vs_kq * 4 + 3];                          \
        vreg0 = *(const float4*)(value + (bhN + (size_t)vr0_) * DDIM + vs_dg * 4); \
        vreg1 = *(const float4*)(value + (bhN + (size_t)vr1_) * DDIM + vs_dg * 4); \
        vreg2 = *(const float4*)(value + (bhN + (size_t)vr2_) * DDIM + vs_dg * 4); \
        vreg3 = *(const float4*)(value + (bhN + (size_t)vr3_) * DDIM + vs_dg * 4); \
    } while (0)

    // chunk-0 loads in flight while we gather Q fragments
    ISSUE_LOADS(0);

    // ---- Q fragments (per-lane: Q[w*64+ni*16+nrow][k2*32+quad*8+j]) ----
    v8h qf[4][2];
    #pragma unroll
    for (int ni = 0; ni < 4; ++ni) {
        int qi = s_qi[w * 64 + ni * 16 + nrow];
        const float* qp = query + (bhN + (size_t)qi) * DDIM;
        #pragma unroll
        for (int k2 = 0; k2 < 2; ++k2) {
            const float4* q4 = (const float4*)(qp + k2 * 32 + quad * 8);
            float4 a = q4[0], bvec = q4[1];
            v8h h;
            h[0]=(_Float16)a.x; h[1]=(_Float16)a.y; h[2]=(_Float16)a.z; h[3]=(_Float16)a.w;
            h[4]=(_Float16)bvec.x; h[5]=(_Float16)bvec.y; h[6]=(_Float16)bvec.z; h[7]=(_Float16)bvec.w;
            qf[ni][k2] = h;
        }
    }

    v4f Oacc[4][4];   // [d-tile][q-tile]: O^T rows d=mi2*16+quad*4+r, col q=ni*16+nrow
    float l_part[4];  // per-lane partial of l[q=ni*16+nrow] (this quad's keys)
    #pragma unroll
    for (int ni = 0; ni < 4; ++ni) {
        l_part[ni] = 0.f;
        #pragma unroll
        for (int mi2 = 0; mi2 < 4; ++mi2) Oacc[mi2][ni] = (v4f){0.f, 0.f, 0.f, 0.f};
    }
    _Float16* Pw = Pb + w * 64 * PPITCH;

    #pragma unroll 1
    for (int ch = 0; ch < 8; ++ch) {
        _Float16* Kc = (_Float16*)(smem + (ch & 1) * 18432);
        _Float16* Vt = (_Float16*)(smem + (ch & 1) * 18432 + 9216);

        // ---- write staged K (regs -> f16 LDS, row-major [key][d]) ----
        // first use of kreg/vreg: compiler inserts the vmcnt wait HERE,
        // covered by the previous chunk's compute phase.
        {
            v8h h0, h1;
            h0[0]=(_Float16)kreg0.x; h0[1]=(_Float16)kreg0.y; h0[2]=(_Float16)kreg0.z; h0[3]=(_Float16)kreg0.w;
            h0[4]=(_Float16)kreg1.x; h0[5]=(_Float16)kreg1.y; h0[6]=(_Float16)kreg1.z; h0[7]=(_Float16)kreg1.w;
            h1[0]=(_Float16)kreg2.x; h1[1]=(_Float16)kreg2.y; h1[2]=(_Float16)kreg2.z; h1[3]=(_Float16)kreg2.w;
            h1[4]=(_Float16)kreg3.x; h1[5]=(_Float16)kreg3.y; h1[6]=(_Float16)kreg3.z; h1[7]=(_Float16)kreg3.w;
            *(v8h*)&Kc[kr_r * PITCH + kr_seg * 16] = h0;
            *(v8h*)&Kc[kr_r * PITCH + kr_seg * 16 + 8] = h1;
        }
        // ---- write staged V transposed [d][key] with packed b64 writes ----
        {
            v4h h0, h1, h2, h3;
            h0[0]=(_Float16)vreg0.x; h0[1]=(_Float16)vreg1.x; h0[2]=(_Float16)vreg2.x; h0[3]=(_Float16)vreg3.x;
            h1[0]=(_Float16)vreg0.y; h1[1]=(_Float16)vreg1.y; h1[2]=(_Float16)vreg2.y; h1[3]=(_Float16)vreg3.y;
            h2[0]=(_Float16)vreg0.z; h2[1]=(_Float16)vreg1.z; h2[2]=(_Float16)vreg2.z; h2[3]=(_Float16)vreg3.z;
            h3[0]=(_Float16)vreg0.w; h3[1]=(_Float16)vreg1.w; h3[2]=(_Float16)vreg2.w; h3[3]=(_Float16)vreg3.w;
            *(v4h*)&Vt[(vs_dg * 4 + 0) * PITCH + vs_kq * 4] = h0;
            *(v4h*)&Vt[(vs_dg * 4 + 1) * PITCH + vs_kq * 4] = h1;
            *(v4h*)&Vt[(vs_dg * 4 + 2) * PITCH + vs_kq * 4] = h2;
            *(v4h*)&Vt[(vs_dg * 4 + 3) * PITCH + vs_kq * 4] = h3;
        }
        // issue next chunk's gathers AFTER the stage-write consumed the old
        // ones; these stay in flight across the raw barrier below.
        if (ch < 7) ISSUE_LOADS(ch + 1);

        // raw barrier: LDS visibility only -- vmcnt NOT drained.
        asm volatile("s_waitcnt lgkmcnt(0)" ::: "memory");
        __builtin_amdgcn_s_barrier();
        __builtin_amdgcn_sched_barrier(0);

        #pragma unroll
        for (int ks = 0; ks < 2; ++ks) {
            // ---- S^T = K.Q^T over 32 keys, exp, store P[q][k] (b64) ----
            #pragma unroll
            for (int mi = 0; mi < 2; ++mi) {
                v4f bb = *(const v4f*)&lb[ch * 64 + ks * 32 + mi * 16 + quad * 4];
                const int krow = ks * 32 + mi * 16 + nrow;
                v8h ka0 = *(const v8h*)&Kc[krow * PITCH + quad * 8];
                v8h ka1 = *(const v8h*)&Kc[krow * PITCH + 32 + quad * 8];
                #pragma unroll
                for (int ni = 0; ni < 4; ++ni) {
                    v4f S = (v4f){0.f, 0.f, 0.f, 0.f};
                    S = __builtin_amdgcn_mfma_f32_16x16x32_f16(ka0, qf[ni][0], S, 0, 0, 0);
                    S = __builtin_amdgcn_mfma_f32_16x16x32_f16(ka1, qf[ni][1], S, 0, 0, 0);
                    v4h ph;
                    #pragma unroll
                    for (int r = 0; r < 4; ++r)
                        ph[r] = (_Float16)__builtin_amdgcn_exp2f(fmaf(S[r], SC2, bb[r]));
                    // l accumulation in VALU; sums the same f16-rounded
                    // values the PV MFMA consumes
                    l_part[ni] += ((float)ph[0] + (float)ph[1])
                                + ((float)ph[2] + (float)ph[3]);
                    *(v4h*)&Pw[(ni * 16 + nrow) * PPITCH + mi * 16 + quad * 4] = ph;
                }
            }
            // ---- load P^T frags, accumulate O^T ----
            v8h pbv[4];
            #pragma unroll
            for (int ni = 0; ni < 4; ++ni)
                pbv[ni] = *(const v8h*)&Pw[(ni * 16 + nrow) * PPITCH + quad * 8];
            __builtin_amdgcn_s_setprio(1);
            #pragma unroll
            for (int mi2 = 0; mi2 < 4; ++mi2) {
                v8h va = *(const v8h*)&Vt[(mi2 * 16 + nrow) * PITCH + ks * 32 + quad * 8];
                #pragma unroll
                for (int ni = 0; ni < 4; ++ni)
                    Oacc[mi2][ni] = __builtin_amdgcn_mfma_f32_16x16x32_f16(va, pbv[ni], Oacc[mi2][ni], 0, 0, 0);
            }
            __builtin_amdgcn_s_setprio(0);
        }
    }

    // ---- normalize, write O (f16) to [q][d] pool, cooperative scatter ----
    __syncthreads();
    #pragma unroll
    for (int ni = 0; ni < 4; ++ni) {
        float l = l_part[ni];
        l += __shfl_xor(l, 16);
        l += __shfl_xor(l, 32);
        float inv = 1.0f / l;
        #pragma unroll
        for (int mi2 = 0; mi2 < 4; ++mi2) {
            v4h h;
            #pragma unroll
            for (int r = 0; r < 4; ++r)
                h[r] = (_Float16)(Oacc[mi2][ni][r] * inv);
            *(v4h*)&Ob[(w * 64 + ni * 16 + nrow) * PITCH + mi2 * 16 + quad * 4] = h;
        }
    }
    __syncthreads();

    #pragma unroll
    for (int p = 0; p < 4; ++p) {
        int row = p * 64 + (t >> 2);
        int seg = t & 3;
        const _Float16* src = &Ob[row * PITCH + seg * 16];
        v8h x0 = *(const v8h*)src;
        v8h x1 = *(const v8h*)(src + 8);
        int qi = s_qi[row];
        float4* op = (float4*)(outp + (bhN + (size_t)qi) * DDIM + seg * 16);
        op[0] = make_float4((float)x0[0], (float)x0[1], (float)x0[2], (float)x0[3]);
        op[1] = make_float4((float)x0[4], (float)x0[5], (float)x0[6], (float)x0[7]);
        op[2] = make_float4((float)x1[0], (float)x1[1], (float)x1[2], (float)x1[3]);
        op[3] = make_float4((float)x1[4], (float)x1[5], (float)x1[6], (float)x1[7]);
    }
}

// ---------------------------------------------------------------------------
extern "C" void kernel_launch(void* const* d_in, const int* in_sizes, int n_in,
                              void* d_out, int out_size, void* d_ws, size_t ws_size,
                              hipStream_t stream) {
    (void)in_sizes; (void)n_in; (void)out_size; (void)ws_size;
    const float* query = (const float*)d_in[0];
    const float* key   = (const float*)d_in[1];
    const float* value = (const float*)d_in[2];
    const float* proj  = (const float*)d_in[3];
    const int* sampled = (const int*)d_in[4];
    float* out = (float*)d_out;

    int* buckets = (int*)d_ws;
    int* q_idx   = buckets + 2 * BH * NSEQ;
    int* k_idx   = q_idx + BH * NSEQ;

    hash_kernel<<<dim3(BH * NSEQ / 256, 2), 256, 0, stream>>>(query, key, proj, buckets);
    sort_kernel<<<dim3(BH, 2), 256, 0, stream>>>(buckets, q_idx, k_idx);
    attn_kernel<<<dim3(NB, BH), 256, 0, stream>>>(query, key, value, sampled,
                                                  q_idx, k_idx, out);
}